// Round 4
// baseline (132.282 us; speedup 1.0000x reference)
//
#include <hip/hip_runtime.h>
#include <hip/hip_bf16.h>
#include <math.h>

#define T_ 16
#define B_ 1024
#define F_ 512
#define H_ 128
#define D_ 8
#define C_ 100
#define L_ 512
#define CP_ 112   // C padded to multiple of 16 for MFMA N

typedef __attribute__((ext_vector_type(8))) short bf16x8_t;
typedef __attribute__((ext_vector_type(4))) float f32x4_t;

__device__ inline ushort f2bf(float x) {
  __hip_bfloat16 b = __float2bfloat16(x);
  return *(ushort*)&b;
}
__device__ inline float bf2f(ushort u) {
  union { unsigned int i; float f; } v;
  v.i = ((unsigned int)u) << 16;
  return v.f;
}

// ---------------------------------------------------------------------------
// k_prep: fused independent preprocessing, block-range dispatch (unchanged
// from round 3 -- keep the k12 experiment single-variable).
// ---------------------------------------------------------------------------
__global__ __launch_bounds__(256) void k_prep(
    const float* __restrict__ feat, const float* __restrict__ W1,
    const float* __restrict__ W2, const float* __restrict__ pi,
    ushort* __restrict__ feat_bf, ushort* __restrict__ W1T,
    ushort* __restrict__ W2T, ushort* __restrict__ lpT) {
  __shared__ ushort ubuf[112 * 48];                  // 10752 B, aliased
  float (*tile)[33] = (float(*)[33])ubuf;            // transpose path (4224 B)
  ushort (*tileT)[48] = (ushort(*)[48])ubuf;         // softmax path
  const int bid = blockIdx.x, tid = threadIdx.x;

  if (bid < 256) {  // ---- feat cvt
    int i = (bid * 256 + tid) * 8;
    float4 a = *(const float4*)(feat + i);
    float4 b = *(const float4*)(feat + i + 4);
    bf16x8_t o;
    o[0] = (short)f2bf(a.x); o[1] = (short)f2bf(a.y);
    o[2] = (short)f2bf(a.z); o[3] = (short)f2bf(a.w);
    o[4] = (short)f2bf(b.x); o[5] = (short)f2bf(b.y);
    o[6] = (short)f2bf(b.z); o[7] = (short)f2bf(b.w);
    *(bf16x8_t*)(feat_bf + i) = o;
    return;
  }
  if (bid < 2304) {  // ---- transposes
    const float* X; ushort* XT; int K, N, kb, nb, s;
    if (bid < 1280) {
      int r = bid - 256;  kb = r & 15; nb = (r >> 4) & 3;  s = r >> 6;
      X = W1; XT = W1T; K = F_; N = H_;
    } else {
      int r = bid - 1280; kb = r & 3;  nb = (r >> 2) & 15; s = r >> 6;
      X = W2; XT = W2T; K = H_; N = L_;
    }
    const int k0 = kb * 32, n0 = nb * 32;
    const int c = tid & 31, r0 = tid >> 5;
    const float* Xs = X + (size_t)s * K * N;
    ushort* XTs = XT + (size_t)s * N * K;
#pragma unroll
    for (int j = 0; j < 4; ++j)
      tile[r0 + 8 * j][c] = Xs[(size_t)(k0 + r0 + 8 * j) * N + n0 + c];
    __syncthreads();
#pragma unroll
    for (int j = 0; j < 4; ++j)
      XTs[(size_t)(n0 + r0 + 8 * j) * K + k0 + c] = f2bf(tile[c][r0 + 8 * j]);
    return;
  }
  {  // ---- softmax of 32 rows -> LDS transpose -> coalesced lpT[t][c][l]
    int bid2 = bid - 2304;                 // [0,256)
    int t = bid2 >> 4, l0 = (bid2 & 15) << 5;
    int lane = tid & 63;
#pragma unroll
    for (int p = 0; p < 8; ++p) {
      int rl = p * 4 + (tid >> 6);
      const float* x = pi + (size_t)(t * L_ + l0 + rl) * C_;
      float v0 = (lane < C_) ? x[lane] : -1e30f;
      float v1 = (lane + 64 < C_) ? x[lane + 64] : -1e30f;
      float m = fmaxf(v0, v1);
#pragma unroll
      for (int off = 32; off; off >>= 1) m = fmaxf(m, __shfl_xor(m, off, 64));
      float e0 = __expf(v0 - m);
      float e1 = (lane + 64 < C_) ? __expf(v1 - m) : 0.0f;
      float sm = e0 + e1;
#pragma unroll
      for (int off = 32; off; off >>= 1) sm += __shfl_xor(sm, off, 64);
      float inv = 1.0f / sm;
      if (lane < C_) tileT[lane][rl] = f2bf(e0 * inv);
      int c2 = lane + 64;
      if (c2 < CP_) tileT[c2][rl] = f2bf(c2 < C_ ? e1 * inv : 0.0f);
    }
    __syncthreads();
    ushort* dst = lpT + (size_t)t * CP_ * L_ + l0;
    for (int idx = tid; idx < 448; idx += 256) {       // 112 c x 4 chunks
      int c = idx >> 2, ch = (idx & 3) * 8;
      *(bf16x8_t*)(dst + (size_t)c * L_ + ch) = *(const bf16x8_t*)&tileT[c][ch];
    }
  }
}

// ---------------------------------------------------------------------------
// k12: fused GEMM1+relu -> h_s, GEMM2+sigmoid -> p_s, tree routing -> mu
// (overwrites p_s), GEMM3 -> part.  ROUND 4: 16-row blocks, grid 1024,
// LDS 40576 B -> 4 blocks/CU (was 2), 4 waves/SIMD -- k12 is latency-bound
// (round 2: +19.7us when B went latency-exposed), so double the TLP.
// t = bid & 15 keeps XCD L2 affinity (XCD x serves t in {x, x+8}).
// ---------------------------------------------------------------------------
__global__ __launch_bounds__(256, 4) void k12_mfma(
    const ushort* __restrict__ feat, const ushort* __restrict__ W1T,
    const float* __restrict__ b1, const ushort* __restrict__ W2T,
    const float* __restrict__ b2, const ushort* __restrict__ lpT,
    float* __restrict__ part) {
  __shared__ ushort smem[20288];                        // 40576 B
  ushort (*a_s)[68]  = (ushort(*)[68])smem;             // [16][68]  ph1 @0
  ushort (*b_s)[68]  = (ushort(*)[68])(smem + 1088);    // [128][68] ph1
  ushort (*w_s)[136] = (ushort(*)[136])smem;            // [64][136] ph2 (aliases ph1 staging)
  ushort (*h_s)[136] = (ushort(*)[136])(smem + 9792);   // [16][136] disjoint
  ushort (*p_s)[520] = (ushort(*)[520])(smem + 11968);  // [16][520] disjoint

  const int bid = blockIdx.x;
  const int t = bid & 15, b0 = (bid >> 4) * 16;
  const int tid = threadIdx.x;
  const int w = tid >> 6, lane = tid & 63, quad = lane >> 4, n = lane & 15;

  // ---------------- phase 1: h tile (M=16, N=128, K=512) ----------------
  {
    f32x4_t acc[2];
    acc[0] = (f32x4_t){0.f, 0.f, 0.f, 0.f};
    acc[1] = (f32x4_t){0.f, 0.f, 0.f, 0.f};

    for (int kc = 0; kc < 8; ++kc) {
      __syncthreads();
      if (tid < 128) {
        int row = tid >> 3, col8 = (tid & 7) * 8;
        *(bf16x8_t*)&a_s[row][col8] =
            *(const bf16x8_t*)(feat + (size_t)(b0 + row) * F_ + kc * 64 + col8);
      }
#pragma unroll
      for (int i = 0; i < 4; ++i) {
        int idx = i * 256 + tid;
        int row = idx >> 3, col8 = (idx & 7) * 8;
        *(bf16x8_t*)&b_s[row][col8] =
            *(const bf16x8_t*)(W1T + ((size_t)t * H_ + row) * F_ + kc * 64 + col8);
      }
      __syncthreads();
#pragma unroll
      for (int ks = 0; ks < 64; ks += 32) {
        bf16x8_t af = *(const bf16x8_t*)&a_s[n][ks + quad * 8];
        bf16x8_t bfr0 = *(const bf16x8_t*)&b_s[w * 32 + n][ks + quad * 8];
        bf16x8_t bfr1 = *(const bf16x8_t*)&b_s[w * 32 + 16 + n][ks + quad * 8];
        acc[0] = __builtin_amdgcn_mfma_f32_16x16x32_bf16(af, bfr0, acc[0],
                                                         0, 0, 0);
        acc[1] = __builtin_amdgcn_mfma_f32_16x16x32_bf16(af, bfr1, acc[1],
                                                         0, 0, 0);
      }
    }
    float bias[2] = {b1[t * H_ + w * 32 + n], b1[t * H_ + w * 32 + 16 + n]};
#pragma unroll
    for (int nt = 0; nt < 2; ++nt)
#pragma unroll
      for (int r = 0; r < 4; ++r) {
        float v = acc[nt][r] + bias[nt];
        h_s[quad * 4 + r][w * 32 + nt * 16 + n] = f2bf(v > 0.f ? v : 0.f);
      }
  }
  __syncthreads();   // h_s complete; ph1 staging region dead

  // ---------------- phase 2: GEMM2 + sigmoid -> p_s ----------------
  {
    bf16x8_t af2[4];                                     // A frags hoisted
#pragma unroll
    for (int ks = 0; ks < 4; ++ks)
      af2[ks] = *(const bf16x8_t*)&h_s[n][ks * 32 + quad * 8];

    for (int nc = 0; nc < 8; ++nc) {
      __syncthreads();   // prev compute's w_s reads done before re-stage
#pragma unroll
      for (int i = 0; i < 4; ++i) {
        int idx = i * 256 + tid;
        int row = idx >> 4, col8 = (idx & 15) * 8;
        *(bf16x8_t*)&w_s[row][col8] =
            *(const bf16x8_t*)(W2T + ((size_t)t * L_ + nc * 64 + row) * H_ + col8);
      }
      __syncthreads();
      f32x4_t acc = (f32x4_t){0.f, 0.f, 0.f, 0.f};
#pragma unroll
      for (int ks = 0; ks < 4; ++ks) {
        bf16x8_t bfrag = *(const bf16x8_t*)&w_s[w * 16 + n][ks * 32 + quad * 8];
        acc = __builtin_amdgcn_mfma_f32_16x16x32_bf16(af2[ks], bfrag, acc,
                                                      0, 0, 0);
      }
      int l = nc * 64 + w * 16 + n;
      float bias = b2[t * L_ + l];
#pragma unroll
      for (int r = 0; r < 4; ++r) {
        float x = acc[r] + bias;
        p_s[quad * 4 + r][l] = f2bf(1.0f / (1.0f + __expf(-x)));
      }
    }
  }
  __syncthreads();

  // ---------------- routing: (row b, 16-leaf subtree s) -> mu in regs ----
  bf16x8_t mo[2][2];
#pragma unroll
  for (int pass = 0; pass < 2; ++pass) {
    int b = pass * 8 + (tid >> 5);
    int s = tid & 31;
    float P = 1.f;
#pragma unroll
    for (int d = 0; d < 5; ++d) {
      int nd = (1 << d) - 1 + (s >> (5 - d));
      int sd = (s >> (4 - d)) & 1;
      float pv = bf2f(p_s[b][nd]);
      P *= sd ? (1.f - pv) : pv;
    }
    float p5 = bf2f(p_s[b][31 + s]);
    float q5[2] = {P * p5, P * (1.f - p5)};
    float q6[4], q7[8];
#pragma unroll
    for (int j = 0; j < 2; ++j) {
      float pv = bf2f(p_s[b][63 + 2 * s + j]);
      q6[2 * j] = q5[j] * pv;
      q6[2 * j + 1] = q5[j] * (1.f - pv);
    }
#pragma unroll
    for (int u = 0; u < 4; ++u) {
      float pv = bf2f(p_s[b][127 + 4 * s + u]);
      q7[2 * u] = q6[u] * pv;
      q7[2 * u + 1] = q6[u] * (1.f - pv);
    }
    bf16x8_t o0, o1;
#pragma unroll
    for (int v = 0; v < 8; ++v) {
      float pv = bf2f(p_s[b][255 + 8 * s + v]);
      ushort e0 = f2bf(q7[v] * pv);
      ushort e1 = f2bf(q7[v] * (1.f - pv));
      if (v < 4) { o0[2 * v] = (short)e0; o0[2 * v + 1] = (short)e1; }
      else       { o1[2 * (v - 4)] = (short)e0; o1[2 * (v - 4) + 1] = (short)e1; }
    }
    mo[pass][0] = o0;
    mo[pass][1] = o1;
  }
  __syncthreads();   // all routing reads of p_s done -> safe to overwrite
#pragma unroll
  for (int pass = 0; pass < 2; ++pass) {
    int b = pass * 8 + (tid >> 5);
    int s = tid & 31;
    *(bf16x8_t*)&p_s[b][s * 16]     = mo[pass][0];   // p_s now holds mu
    *(bf16x8_t*)&p_s[b][s * 16 + 8] = mo[pass][1];
  }
  __syncthreads();

  // ---------------- GEMM3: part[t][b][c] = mu @ leaf_p (M=16,N=112,K=512) --
  // wave w: nt tiles {2w, 2w+1} (w=3: just {6}).  B direct from L2 lpT.
  {
    const int nt0 = w * 2;
    const int ncnt = (w == 3) ? 1 : 2;
    const ushort* arow = &p_s[n][0];
    const ushort* brow = lpT + (size_t)t * CP_ * L_ +
                         ((size_t)(nt0 * 16 + n)) * L_ + quad * 8;
    f32x4_t acc[2];
    acc[0] = (f32x4_t){0.f, 0.f, 0.f, 0.f};
    acc[1] = (f32x4_t){0.f, 0.f, 0.f, 0.f};
#pragma unroll 4
    for (int k = 0; k < L_; k += 32) {
      bf16x8_t af = *(const bf16x8_t*)(arow + k + quad * 8);
#pragma unroll
      for (int j = 0; j < 2; ++j) {
        if (j < ncnt) {
          bf16x8_t bfr = *(const bf16x8_t*)(brow + (size_t)j * 16 * L_ + k);
          acc[j] = __builtin_amdgcn_mfma_f32_16x16x32_bf16(af, bfr, acc[j],
                                                           0, 0, 0);
        }
      }
    }
    const int m0 = b0 + quad * 4;
#pragma unroll
    for (int j = 0; j < 2; ++j) {
      int c = (nt0 + j) * 16 + n;
      if (j < ncnt && c < C_) {
#pragma unroll
        for (int r = 0; r < 4; ++r)
          part[((size_t)t * B_ + m0 + r) * C_ + c] = acc[j][r];
      }
    }
  }
}

// ---------------------------------------------------------------------------
// k6: out[b][c] = log( (sum_t part[t][b][c]) / (L*T) )
// ---------------------------------------------------------------------------
__global__ __launch_bounds__(256) void k6_log(
    const float* __restrict__ part, float* __restrict__ out) {
  int i = blockIdx.x * 256 + threadIdx.x;
  if (i < B_ * C_) {
    float s = 0.0f;
#pragma unroll
    for (int t = 0; t < T_; ++t) s += part[(size_t)t * B_ * C_ + i];
    out[i] = logf(s * (1.0f / (L_ * T_)));
  }
}

extern "C" void kernel_launch(void* const* d_in, const int* in_sizes, int n_in,
                              void* d_out, int out_size, void* d_ws,
                              size_t ws_size, hipStream_t stream) {
  const float* feat = (const float*)d_in[0];
  const float* W1   = (const float*)d_in[1];
  const float* b1   = (const float*)d_in[2];
  const float* W2   = (const float*)d_in[3];
  const float* b2   = (const float*)d_in[4];
  const float* pi   = (const float*)d_in[5];
  float* out = (float*)d_out;

  char* ws = (char*)d_ws;
  ushort* feat_bf  = (ushort*)(ws);                                // 1 MB
  ushort* W1T_buf  = (ushort*)(ws + ((size_t)1 << 20));            // 2 MB
  ushort* W2T_buf  = (ushort*)(ws + ((size_t)3 << 20));            // 2 MB
  ushort* lpT_buf  = (ushort*)(ws + ((size_t)5 << 20));            // 1.75 MB
  float*  part_buf = (float*)(ws + ((size_t)7 << 20));             // 6.25 MB

  k_prep<<<2560, 256, 0, stream>>>(feat, W1, W2, pi, feat_bf, W1T_buf,
                                   W2T_buf, lpT_buf);
  k12_mfma<<<1024, 256, 0, stream>>>(feat_bf, W1T_buf, b1, W2T_buf, b2,
                                     lpT_buf, part_buf);
  k6_log<<<(B_ * C_ + 255) / 256, 256, 0, stream>>>(part_buf, out);
}

// Round 5
// 110.550 us; speedup vs baseline: 1.1966x; 1.1966x over previous
//
#include <hip/hip_runtime.h>
#include <hip/hip_bf16.h>
#include <math.h>

#define T_ 16
#define B_ 1024
#define F_ 512
#define H_ 128
#define D_ 8
#define C_ 100
#define L_ 512
#define CP_ 112   // C padded to multiple of 16 for MFMA N

typedef __attribute__((ext_vector_type(8))) short bf16x8_t;
typedef __attribute__((ext_vector_type(4))) float f32x4_t;

__device__ inline ushort f2bf(float x) {
  __hip_bfloat16 b = __float2bfloat16(x);
  return *(ushort*)&b;
}
__device__ inline float bf2f(ushort u) {
  union { unsigned int i; float f; } v;
  v.i = ((unsigned int)u) << 16;
  return v.f;
}

// ---------------------------------------------------------------------------
// k_prep: unchanged from round 3 (single-variable discipline on k12).
// ---------------------------------------------------------------------------
__global__ __launch_bounds__(256) void k_prep(
    const float* __restrict__ feat, const float* __restrict__ W1,
    const float* __restrict__ W2, const float* __restrict__ pi,
    ushort* __restrict__ feat_bf, ushort* __restrict__ W1T,
    ushort* __restrict__ W2T, ushort* __restrict__ lpT) {
  __shared__ ushort ubuf[112 * 48];                  // 10752 B, aliased
  float (*tile)[33] = (float(*)[33])ubuf;            // transpose path (4224 B)
  ushort (*tileT)[48] = (ushort(*)[48])ubuf;         // softmax path
  const int bid = blockIdx.x, tid = threadIdx.x;

  if (bid < 256) {  // ---- feat cvt
    int i = (bid * 256 + tid) * 8;
    float4 a = *(const float4*)(feat + i);
    float4 b = *(const float4*)(feat + i + 4);
    bf16x8_t o;
    o[0] = (short)f2bf(a.x); o[1] = (short)f2bf(a.y);
    o[2] = (short)f2bf(a.z); o[3] = (short)f2bf(a.w);
    o[4] = (short)f2bf(b.x); o[5] = (short)f2bf(b.y);
    o[6] = (short)f2bf(b.z); o[7] = (short)f2bf(b.w);
    *(bf16x8_t*)(feat_bf + i) = o;
    return;
  }
  if (bid < 2304) {  // ---- transposes
    const float* X; ushort* XT; int K, N, kb, nb, s;
    if (bid < 1280) {
      int r = bid - 256;  kb = r & 15; nb = (r >> 4) & 3;  s = r >> 6;
      X = W1; XT = W1T; K = F_; N = H_;
    } else {
      int r = bid - 1280; kb = r & 3;  nb = (r >> 2) & 15; s = r >> 6;
      X = W2; XT = W2T; K = H_; N = L_;
    }
    const int k0 = kb * 32, n0 = nb * 32;
    const int c = tid & 31, r0 = tid >> 5;
    const float* Xs = X + (size_t)s * K * N;
    ushort* XTs = XT + (size_t)s * N * K;
#pragma unroll
    for (int j = 0; j < 4; ++j)
      tile[r0 + 8 * j][c] = Xs[(size_t)(k0 + r0 + 8 * j) * N + n0 + c];
    __syncthreads();
#pragma unroll
    for (int j = 0; j < 4; ++j)
      XTs[(size_t)(n0 + r0 + 8 * j) * K + k0 + c] = f2bf(tile[c][r0 + 8 * j]);
    return;
  }
  {  // ---- softmax of 32 rows -> LDS transpose -> coalesced lpT[t][c][l]
    int bid2 = bid - 2304;                 // [0,256)
    int t = bid2 >> 4, l0 = (bid2 & 15) << 5;
    int lane = tid & 63;
#pragma unroll
    for (int p = 0; p < 8; ++p) {
      int rl = p * 4 + (tid >> 6);
      const float* x = pi + (size_t)(t * L_ + l0 + rl) * C_;
      float v0 = (lane < C_) ? x[lane] : -1e30f;
      float v1 = (lane + 64 < C_) ? x[lane + 64] : -1e30f;
      float m = fmaxf(v0, v1);
#pragma unroll
      for (int off = 32; off; off >>= 1) m = fmaxf(m, __shfl_xor(m, off, 64));
      float e0 = __expf(v0 - m);
      float e1 = (lane + 64 < C_) ? __expf(v1 - m) : 0.0f;
      float sm = e0 + e1;
#pragma unroll
      for (int off = 32; off; off >>= 1) sm += __shfl_xor(sm, off, 64);
      float inv = 1.0f / sm;
      if (lane < C_) tileT[lane][rl] = f2bf(e0 * inv);
      int c2 = lane + 64;
      if (c2 < CP_) tileT[c2][rl] = f2bf(c2 < C_ ? e1 * inv : 0.0f);
    }
    __syncthreads();
    ushort* dst = lpT + (size_t)t * CP_ * L_ + l0;
    for (int idx = tid; idx < 448; idx += 256) {       // 112 c x 4 chunks
      int c = idx >> 2, ch = (idx & 3) * 8;
      *(bf16x8_t*)(dst + (size_t)c * L_ + ch) = *(const bf16x8_t*)&tileT[c][ch];
    }
  }
}

// ---------------------------------------------------------------------------
// k12: round-3 32-row structure + T14 issue-early staging.  Per staging
// phase, global loads for chunk k+1 are ISSUED before compute of chunk k;
// the vmcnt wait lands at the ds_write after the post-compute barrier, so
// L2 latency (~300cy) hides under MFMA instead of the critical path.
// Round-4 evidence: k12 was 83% idle (MfmaUtil 4%, VALUBusy 13%) -- pure
// exposed-latency stall.  grid 512, 59392 B LDS, 2 blocks/CU,
// t = bid & 15 keeps XCD L2 affinity.
// ---------------------------------------------------------------------------
__global__ __launch_bounds__(256) void k12_mfma(
    const ushort* __restrict__ feat, const ushort* __restrict__ W1T,
    const float* __restrict__ b1, const ushort* __restrict__ W2T,
    const float* __restrict__ b2, const ushort* __restrict__ lpT,
    float* __restrict__ part) {
  __shared__ ushort smem[29696];                        // 59392 B
  ushort (*h_s)[136] = (ushort(*)[136])smem;            // [32][136] @0
  ushort (*a_s)[72]  = (ushort(*)[72])(smem + 4352);    // [32][72]  ph1
  ushort (*b_s)[72]  = (ushort(*)[72])(smem + 6656);    // [128][72] ph1
  ushort (*w_s)[136] = (ushort(*)[136])(smem + 4352);   // [64][136] ph2
  ushort (*p_s)[520] = (ushort(*)[520])(smem + 13056);  // [32][520] ph2 + mu

  const int bid = blockIdx.x;
  const int t = bid & 15, b0 = (bid >> 4) * 32;
  const int tid = threadIdx.x;
  const int w = tid >> 6, lane = tid & 63, quad = lane >> 4, n = lane & 15;

  // staging maps (identical data placement to round 3)
  const int arow = tid >> 3, acol = (tid & 7) * 8;      // ph1: A row, B row+i*32
  const ushort* featp = feat + (size_t)(b0 + arow) * F_ + acol;
  const ushort* w1p   = W1T + ((size_t)t * H_ + arow) * F_ + acol;

  // ---------------- phase 1: h tile (M=32, N=128, K=512) ----------------
  {
    f32x4_t acc[2][2];
#pragma unroll
    for (int i = 0; i < 2; ++i)
#pragma unroll
      for (int j = 0; j < 2; ++j) acc[i][j] = (f32x4_t){0.f, 0.f, 0.f, 0.f};

    bf16x8_t ra, rb[4];
    // prologue: load + stage kc=0 (latency exposed once)
    ra = *(const bf16x8_t*)(featp);
#pragma unroll
    for (int i = 0; i < 4; ++i)
      rb[i] = *(const bf16x8_t*)(w1p + (size_t)i * 32 * F_);
    *(bf16x8_t*)&a_s[arow][acol] = ra;
#pragma unroll
    for (int i = 0; i < 4; ++i)
      *(bf16x8_t*)&b_s[i * 32 + arow][acol] = rb[i];
    __syncthreads();
    // issue kc=1 (in flight during compute of kc=0)
    ra = *(const bf16x8_t*)(featp + 64);
#pragma unroll
    for (int i = 0; i < 4; ++i)
      rb[i] = *(const bf16x8_t*)(w1p + (size_t)i * 32 * F_ + 64);

#pragma unroll
    for (int kc = 0; kc < 8; ++kc) {
#pragma unroll
      for (int ks = 0; ks < 64; ks += 32) {
        bf16x8_t af[2], bfr[2];
#pragma unroll
        for (int mt = 0; mt < 2; ++mt)
          af[mt] = *(const bf16x8_t*)&a_s[mt * 16 + n][ks + quad * 8];
#pragma unroll
        for (int nt = 0; nt < 2; ++nt)
          bfr[nt] = *(const bf16x8_t*)&b_s[w * 32 + nt * 16 + n][ks + quad * 8];
#pragma unroll
        for (int mt = 0; mt < 2; ++mt)
#pragma unroll
          for (int nt = 0; nt < 2; ++nt)
            acc[mt][nt] = __builtin_amdgcn_mfma_f32_16x16x32_bf16(
                af[mt], bfr[nt], acc[mt][nt], 0, 0, 0);
      }
      __syncthreads();                       // all reads of a_s/b_s done
      if (kc < 7) {
        *(bf16x8_t*)&a_s[arow][acol] = ra;   // vmcnt wait lands here
#pragma unroll
        for (int i = 0; i < 4; ++i)
          *(bf16x8_t*)&b_s[i * 32 + arow][acol] = rb[i];
        __syncthreads();                     // staged kc+1 visible
        if (kc < 6) {                        // issue kc+2
          ra = *(const bf16x8_t*)(featp + (kc + 2) * 64);
#pragma unroll
          for (int i = 0; i < 4; ++i)
            rb[i] = *(const bf16x8_t*)(w1p + (size_t)i * 32 * F_ + (kc + 2) * 64);
        }
      }
    }
    float bias[2] = {b1[t * H_ + w * 32 + n], b1[t * H_ + w * 32 + 16 + n]};
#pragma unroll
    for (int mt = 0; mt < 2; ++mt)
#pragma unroll
      for (int nt = 0; nt < 2; ++nt)
#pragma unroll
        for (int r = 0; r < 4; ++r) {
          int row = mt * 16 + quad * 4 + r;
          int col = w * 32 + nt * 16 + n;
          float v = acc[mt][nt][r] + bias[nt];
          h_s[row][col] = f2bf(v > 0.f ? v : 0.f);   // h_s region: no hazard
        }
  }

  // ---------------- phase 2: GEMM2 + sigmoid -> p_s ----------------
  {
    const int wrow = tid >> 4, wcol = (tid & 15) * 8;  // rows i*16+wrow
    const ushort* w2p = W2T + ((size_t)t * L_ + wrow) * H_ + wcol;
    bf16x8_t rw[4];
    // issue nc=0 W-loads NOW -- they fly under the epilogue + barrier
#pragma unroll
    for (int i = 0; i < 4; ++i)
      rw[i] = *(const bf16x8_t*)(w2p + (size_t)(i * 16) * H_);
    __syncthreads();   // h_s visible; ph1 staging region dead

    bf16x8_t af2[2][4];                                // A frags hoisted
#pragma unroll
    for (int mt = 0; mt < 2; ++mt)
#pragma unroll
      for (int ks = 0; ks < 4; ++ks)
        af2[mt][ks] = *(const bf16x8_t*)&h_s[mt * 16 + n][ks * 32 + quad * 8];
#pragma unroll
    for (int i = 0; i < 4; ++i)
      *(bf16x8_t*)&w_s[i * 16 + wrow][wcol] = rw[i];
    __syncthreads();                                   // w_s(0) visible
    // issue nc=1
#pragma unroll
    for (int i = 0; i < 4; ++i)
      rw[i] = *(const bf16x8_t*)(w2p + (size_t)(64 + i * 16) * H_);

#pragma unroll
    for (int nc = 0; nc < 8; ++nc) {
      f32x4_t acc[2];
      acc[0] = (f32x4_t){0.f, 0.f, 0.f, 0.f};
      acc[1] = (f32x4_t){0.f, 0.f, 0.f, 0.f};
#pragma unroll
      for (int ks = 0; ks < 4; ++ks) {
        bf16x8_t bfrag = *(const bf16x8_t*)&w_s[w * 16 + n][ks * 32 + quad * 8];
        acc[0] = __builtin_amdgcn_mfma_f32_16x16x32_bf16(af2[0][ks], bfrag,
                                                         acc[0], 0, 0, 0);
        acc[1] = __builtin_amdgcn_mfma_f32_16x16x32_bf16(af2[1][ks], bfrag,
                                                         acc[1], 0, 0, 0);
      }
      int l = nc * 64 + w * 16 + n;
      float bias = b2[t * L_ + l];
#pragma unroll
      for (int mt = 0; mt < 2; ++mt)
#pragma unroll
        for (int r = 0; r < 4; ++r) {
          float x = acc[mt][r] + bias;
          p_s[mt * 16 + quad * 4 + r][l] = f2bf(1.0f / (1.0f + __expf(-x)));
        }
      __syncthreads();                       // w_s reads + p_s writes done
      if (nc < 7) {
#pragma unroll
        for (int i = 0; i < 4; ++i)
          *(bf16x8_t*)&w_s[i * 16 + wrow][wcol] = rw[i];   // vmcnt wait here
        __syncthreads();                     // w_s(nc+1) visible
        if (nc < 6) {                        // issue nc+2
#pragma unroll
          for (int i = 0; i < 4; ++i)
            rw[i] = *(const bf16x8_t*)(w2p + (size_t)((nc + 2) * 64 + i * 16) * H_);
        }
      }
    }
  }
  __syncthreads();

  // ---------------- routing: (row b, 16-leaf subtree s) -> mu in regs ----
  bf16x8_t mo[4][2];
#pragma unroll
  for (int pass = 0; pass < 4; ++pass) {
    int b = pass * 8 + (tid >> 5);
    int s = tid & 31;
    float P = 1.f;
#pragma unroll
    for (int d = 0; d < 5; ++d) {
      int nd = (1 << d) - 1 + (s >> (5 - d));
      int sd = (s >> (4 - d)) & 1;
      float pv = bf2f(p_s[b][nd]);
      P *= sd ? (1.f - pv) : pv;
    }
    float p5 = bf2f(p_s[b][31 + s]);
    float q5[2] = {P * p5, P * (1.f - p5)};
    float q6[4], q7[8];
#pragma unroll
    for (int j = 0; j < 2; ++j) {
      float pv = bf2f(p_s[b][63 + 2 * s + j]);
      q6[2 * j] = q5[j] * pv;
      q6[2 * j + 1] = q5[j] * (1.f - pv);
    }
#pragma unroll
    for (int u = 0; u < 4; ++u) {
      float pv = bf2f(p_s[b][127 + 4 * s + u]);
      q7[2 * u] = q6[u] * pv;
      q7[2 * u + 1] = q6[u] * (1.f - pv);
    }
    bf16x8_t o0, o1;
#pragma unroll
    for (int v = 0; v < 8; ++v) {
      float pv = bf2f(p_s[b][255 + 8 * s + v]);
      ushort e0 = f2bf(q7[v] * pv);
      ushort e1 = f2bf(q7[v] * (1.f - pv));
      if (v < 4) { o0[2 * v] = (short)e0; o0[2 * v + 1] = (short)e1; }
      else       { o1[2 * (v - 4)] = (short)e0; o1[2 * (v - 4) + 1] = (short)e1; }
    }
    mo[pass][0] = o0;
    mo[pass][1] = o1;
  }
  __syncthreads();   // all routing reads of p_s done -> safe to overwrite
#pragma unroll
  for (int pass = 0; pass < 4; ++pass) {
    int b = pass * 8 + (tid >> 5);
    int s = tid & 31;
    *(bf16x8_t*)&p_s[b][s * 16]     = mo[pass][0];   // p_s now holds mu
    *(bf16x8_t*)&p_s[b][s * 16 + 8] = mo[pass][1];
  }
  __syncthreads();

  // ---------------- GEMM3: part[t][b][c] = mu @ leaf_p (M=32,N=112,K=512) --
  {
    const int mt = w >> 1;
    const int nt0 = (w & 1) * 4;
    const int ncnt = (w & 1) ? 3 : 4;
    const ushort* arow2 = &p_s[mt * 16 + n][0];
    const ushort* brow = lpT + (size_t)t * CP_ * L_ +
                         ((size_t)(nt0 * 16 + n)) * L_ + quad * 8;
    f32x4_t acc[4];
#pragma unroll
    for (int i = 0; i < 4; ++i) acc[i] = (f32x4_t){0.f, 0.f, 0.f, 0.f};
#pragma unroll 4
    for (int k = 0; k < L_; k += 32) {
      bf16x8_t af = *(const bf16x8_t*)(arow2 + k + quad * 8);
#pragma unroll
      for (int j = 0; j < 4; ++j) {
        if (j < ncnt) {
          bf16x8_t bfr = *(const bf16x8_t*)(brow + (size_t)j * 16 * L_ + k);
          acc[j] = __builtin_amdgcn_mfma_f32_16x16x32_bf16(af, bfr, acc[j],
                                                           0, 0, 0);
        }
      }
    }
    const int m0 = b0 + mt * 16 + quad * 4;
#pragma unroll
    for (int j = 0; j < 4; ++j) {
      int c = (nt0 + j) * 16 + n;
      if (j < ncnt && c < C_) {
#pragma unroll
        for (int r = 0; r < 4; ++r)
          part[((size_t)t * B_ + m0 + r) * C_ + c] = acc[j][r];
      }
    }
  }
}

// ---------------------------------------------------------------------------
// k6: out[b][c] = log( (sum_t part[t][b][c]) / (L*T) )
// ---------------------------------------------------------------------------
__global__ __launch_bounds__(256) void k6_log(
    const float* __restrict__ part, float* __restrict__ out) {
  int i = blockIdx.x * 256 + threadIdx.x;
  if (i < B_ * C_) {
    float s = 0.0f;
#pragma unroll
    for (int t = 0; t < T_; ++t) s += part[(size_t)t * B_ * C_ + i];
    out[i] = logf(s * (1.0f / (L_ * T_)));
  }
}

extern "C" void kernel_launch(void* const* d_in, const int* in_sizes, int n_in,
                              void* d_out, int out_size, void* d_ws,
                              size_t ws_size, hipStream_t stream) {
  const float* feat = (const float*)d_in[0];
  const float* W1   = (const float*)d_in[1];
  const float* b1   = (const float*)d_in[2];
  const float* W2   = (const float*)d_in[3];
  const float* b2   = (const float*)d_in[4];
  const float* pi   = (const float*)d_in[5];
  float* out = (float*)d_out;

  char* ws = (char*)d_ws;
  ushort* feat_bf  = (ushort*)(ws);                                // 1 MB
  ushort* W1T_buf  = (ushort*)(ws + ((size_t)1 << 20));            // 2 MB
  ushort* W2T_buf  = (ushort*)(ws + ((size_t)3 << 20));            // 2 MB
  ushort* lpT_buf  = (ushort*)(ws + ((size_t)5 << 20));            // 1.75 MB
  float*  part_buf = (float*)(ws + ((size_t)7 << 20));             // 6.25 MB

  k_prep<<<2560, 256, 0, stream>>>(feat, W1, W2, pi, feat_bf, W1T_buf,
                                   W2T_buf, lpT_buf);
  k12_mfma<<<512, 256, 0, stream>>>(feat_bf, W1T_buf, b1, W2T_buf, b2,
                                    lpT_buf, part_buf);
  k6_log<<<(B_ * C_ + 255) / 256, 256, 0, stream>>>(part_buf, out);
}